// Round 1
// baseline (89.487 us; speedup 1.0000x reference)
//
#include <hip/hip_runtime.h>
#include <math.h>

#define DD  256
#define LKK 512
#define LQQ 256
#define BB  4

constexpr float TWO_LOG2E = 2.8853900817779268f;  // 2*log2(e)
constexpr float LOG2E     = 1.4426950408889634f;

__device__ __forceinline__ float fast_rcp(float x)  { return __builtin_amdgcn_rcpf(x); }
__device__ __forceinline__ float fast_exp2(float x) { return __builtin_amdgcn_exp2f(x); }

// E[m,e] = exp2( TWO_LOG2E * sum_d X[m,d] * W[e,d] )   (i.e. exp(2 * X @ W^T))
// X: [M][256] row-major, W: [256][256] row-major (e-major), E: [M][256]
__global__ __launch_bounds__(256) void gemm_expk(const float* __restrict__ X,
                                                 const float* __restrict__ W,
                                                 float* __restrict__ E) {
  __shared__ float Xs[16][68];
  __shared__ float Ws[16][68];
  const int tid = threadIdx.x;
  const int tx = tid & 15, ty = tid >> 4;
  const int m0 = blockIdx.x * 64, e0 = blockIdx.y * 64;
  const int lm = tid >> 2;         // 0..63
  const int lk = (tid & 3) << 2;   // 0,4,8,12
  float acc[4][4] = {};
  for (int k0 = 0; k0 < DD; k0 += 16) {
    const float4 xv = *(const float4*)&X[(m0 + lm) * DD + k0 + lk];
    const float4 wv = *(const float4*)&W[(e0 + lm) * DD + k0 + lk];
    __syncthreads();
    Xs[lk + 0][lm] = xv.x; Xs[lk + 1][lm] = xv.y; Xs[lk + 2][lm] = xv.z; Xs[lk + 3][lm] = xv.w;
    Ws[lk + 0][lm] = wv.x; Ws[lk + 1][lm] = wv.y; Ws[lk + 2][lm] = wv.z; Ws[lk + 3][lm] = wv.w;
    __syncthreads();
#pragma unroll
    for (int k = 0; k < 16; ++k) {
      const float4 a  = *(const float4*)&Xs[k][ty << 2];
      const float4 bq = *(const float4*)&Ws[k][tx << 2];
      const float av[4] = {a.x, a.y, a.z, a.w};
      const float bv[4] = {bq.x, bq.y, bq.z, bq.w};
#pragma unroll
      for (int i = 0; i < 4; ++i)
#pragma unroll
        for (int j = 0; j < 4; ++j) acc[i][j] = fmaf(av[i], bv[j], acc[i][j]);
    }
  }
#pragma unroll
  for (int i = 0; i < 4; ++i) {
    float4 o;
    o.x = fast_exp2(acc[i][0] * TWO_LOG2E);
    o.y = fast_exp2(acc[i][1] * TWO_LOG2E);
    o.z = fast_exp2(acc[i][2] * TWO_LOG2E);
    o.w = fast_exp2(acc[i][3] * TWO_LOG2E);
    *(float4*)&E[(m0 + (ty << 2) + i) * DD + e0 + (tx << 2)] = o;
  }
}

// One block per (b, 4 q-rows). 256 threads. Computes scores via
// tanh(a+b) = 1 - 2/(Ea*Eb+1), then softmax, attention out, context out.
__global__ __launch_bounds__(256) void attn_main(const float* __restrict__ Ea,
                                                 const float* __restrict__ Eb,
                                                 const float* __restrict__ vvec,
                                                 const float* __restrict__ value,
                                                 const int* __restrict__ mask,
                                                 float* __restrict__ ctx_out,
                                                 float* __restrict__ attn_out) {
  __shared__ float ebs[4][DD];
  __shared__ float vsh[DD];
  __shared__ float sc[4][LKK];
  const int tid = threadIdx.x;
  const int b  = blockIdx.x >> 6;
  const int q0 = (blockIdx.x & 63) << 2;

  // stage Eb rows (4x256) and v (256) into LDS
  {
    const int q = tid >> 6, c4 = (tid & 63) << 2;
    *(float4*)&ebs[q][c4] = *(const float4*)&Eb[(b * LQQ + q0 + q) * DD + c4];
    if (tid < 64) *(float4*)&vsh[tid << 2] = *(const float4*)&vvec[tid << 2];
  }
  __syncthreads();

  // Sv = sum_d v[d] (redundant per thread, trivial cost)
  float Sv = 0.f;
#pragma unroll 8
  for (int d4 = 0; d4 < 64; ++d4) {
    const float4 vv = *(const float4*)&vsh[d4 << 2];
    Sv += (vv.x + vv.y) + (vv.z + vv.w);
  }

  // scores: thread owns k0=tid and k1=tid+256 for all 4 q-rows
  const int k0 = tid, k1 = tid + 256;
  const float* __restrict__ ea0p = &Ea[(b * LKK + k0) * DD];
  const float* __restrict__ ea1p = &Ea[(b * LKK + k1) * DD];
  float acc0[4] = {}, acc1[4] = {};
  for (int d4 = 0; d4 < 64; ++d4) {
    const float4 ea0 = *(const float4*)&ea0p[d4 << 2];
    const float4 ea1 = *(const float4*)&ea1p[d4 << 2];
    const float4 vv  = *(const float4*)&vsh[d4 << 2];
#pragma unroll
    for (int q = 0; q < 4; ++q) {
      const float4 eb = *(const float4*)&ebs[q][d4 << 2];
      acc0[q] += vv.x * fast_rcp(fmaf(ea0.x, eb.x, 1.f))
               + vv.y * fast_rcp(fmaf(ea0.y, eb.y, 1.f))
               + vv.z * fast_rcp(fmaf(ea0.z, eb.z, 1.f))
               + vv.w * fast_rcp(fmaf(ea0.w, eb.w, 1.f));
      acc1[q] += vv.x * fast_rcp(fmaf(ea1.x, eb.x, 1.f))
               + vv.y * fast_rcp(fmaf(ea1.y, eb.y, 1.f))
               + vv.z * fast_rcp(fmaf(ea1.z, eb.z, 1.f))
               + vv.w * fast_rcp(fmaf(ea1.w, eb.w, 1.f));
    }
  }

  const float inv_scale = 0.0625f;  // 1/sqrt(256)
#pragma unroll
  for (int q = 0; q < 4; ++q) {
    const int row = (b * LQQ + q0 + q) * LKK;
    float s0 = (Sv - 2.f * acc0[q]) * inv_scale;
    float s1 = (Sv - 2.f * acc1[q]) * inv_scale;
    if (mask[row + k0] == 0) s0 = -1e10f;
    if (mask[row + k1] == 0) s1 = -1e10f;
    sc[q][k0] = s0;
    sc[q][k1] = s1;
  }
  __syncthreads();

  // softmax: wave w handles q-row w (512 values, 8 per lane)
  const int w = tid >> 6, lane = tid & 63;
  float e_[8];
  float mx = -3.4e38f;
#pragma unroll
  for (int j = 0; j < 8; ++j) { e_[j] = sc[w][(j << 6) + lane]; mx = fmaxf(mx, e_[j]); }
#pragma unroll
  for (int off = 32; off; off >>= 1) mx = fmaxf(mx, __shfl_xor(mx, off));
  float sum = 0.f;
#pragma unroll
  for (int j = 0; j < 8; ++j) { e_[j] = fast_exp2((e_[j] - mx) * LOG2E); sum += e_[j]; }
#pragma unroll
  for (int off = 32; off; off >>= 1) sum += __shfl_xor(sum, off);
  const float inv_sum = fast_rcp(sum);
  const int arow = (b * LQQ + q0 + w) * LKK;
#pragma unroll
  for (int j = 0; j < 8; ++j) {
    const float a = e_[j] * inv_sum;
    sc[w][(j << 6) + lane] = a;
    attn_out[arow + (j << 6) + lane] = a;
  }
  __syncthreads();

  // context[q, d=tid] = sum_k attn[q,k] * value[b,k,d]
  float c0 = 0.f, c1 = 0.f, c2 = 0.f, c3 = 0.f;
  const float* __restrict__ vbase = &value[b * LKK * DD + tid];
#pragma unroll 8
  for (int k = 0; k < LKK; ++k) {
    const float val = vbase[k * DD];
    c0 = fmaf(sc[0][k], val, c0);
    c1 = fmaf(sc[1][k], val, c1);
    c2 = fmaf(sc[2][k], val, c2);
    c3 = fmaf(sc[3][k], val, c3);
  }
  const int crow = (b * LQQ + q0) * DD + tid;
  ctx_out[crow]          = c0;
  ctx_out[crow + DD]     = c1;
  ctx_out[crow + 2 * DD] = c2;
  ctx_out[crow + 3 * DD] = c3;
}

extern "C" void kernel_launch(void* const* d_in, const int* in_sizes, int n_in,
                              void* d_out, int out_size, void* d_ws, size_t ws_size,
                              hipStream_t stream) {
  const float* query = (const float*)d_in[0];
  const float* key   = (const float*)d_in[1];
  const float* value = (const float*)d_in[2];
  const float* W1    = (const float*)d_in[3];
  const float* W2    = (const float*)d_in[4];
  const float* v     = (const float*)d_in[5];
  const int*   mask  = (const int*)d_in[6];

  float* out      = (float*)d_out;
  float* ctx_out  = out;                       // [B, LQ, D]
  float* attn_out = out + BB * LQQ * DD;       // [B, LQ, LK]

  float* Ea = (float*)d_ws;                    // [B*LK, D] = 2 MB
  float* Eb = Ea + BB * LKK * DD;              // [B*LQ, D] = 1 MB

  dim3 g1(BB * LKK / 64, DD / 64);             // (32, 4)
  gemm_expk<<<g1, 256, 0, stream>>>(key, W1, Ea);
  dim3 g2(BB * LQQ / 64, DD / 64);             // (16, 4)
  gemm_expk<<<g2, 256, 0, stream>>>(query, W2, Eb);

  attn_main<<<256, 256, 0, stream>>>(Ea, Eb, v, value, mask, ctx_out, attn_out);
}

// Round 2
// 75.503 us; speedup vs baseline: 1.1852x; 1.1852x over previous
//
#include <hip/hip_runtime.h>
#include <math.h>

#define DD  256
#define LKK 512
#define LQQ 256
#define BB  4

constexpr float TWO_LOG2E = 2.8853900817779268f;  // 2*log2(e)
constexpr float LOG2E     = 1.4426950408889634f;

__device__ __forceinline__ float fast_rcp(float x)  { return __builtin_amdgcn_rcpf(x); }
__device__ __forceinline__ float fast_exp2(float x) { return __builtin_amdgcn_exp2f(x); }

// Combined: Ea = exp(2 * key @ W1^T)  [B*LK, D],  Eb = exp(2 * query @ W2^T) [B*LQ, D]
// 32x64 output tiles, 256 threads, acc 2x4 per thread. 384 blocks total.
__global__ __launch_bounds__(256) void gemm_expk2(const float* __restrict__ key,
                                                  const float* __restrict__ query,
                                                  const float* __restrict__ W1,
                                                  const float* __restrict__ W2,
                                                  float* __restrict__ Ea,
                                                  float* __restrict__ Eb) {
  __shared__ float Xs[16][36];  // [k][m] , stride 36 keeps float2 16B-safe + bank-spread
  __shared__ float Ws[16][68];  // [k][e] , stride 68 keeps float4 16B-aligned
  const int tid = threadIdx.x;
  const bool isK = blockIdx.x < (BB * LKK / 32);           // 64 key-blocks, 32 query-blocks
  const float* __restrict__ X = isK ? key : query;
  const float* __restrict__ W = isK ? W1 : W2;
  float* __restrict__ E = isK ? Ea : Eb;
  const int m0 = (isK ? blockIdx.x : blockIdx.x - BB * LKK / 32) * 32;
  const int e0 = blockIdx.y * 64;

  const int r0 = (tid >> 4) << 1;   // 0..30 (2 rows)
  const int c0 = (tid & 15) << 2;   // 0..60 (4 cols)
  const int xr = tid >> 3, xc = (tid & 7) << 1;   // stage X: 32x16 via float2
  const int wr = tid >> 2, wc = (tid & 3) << 2;   // stage W: 64x16 via float4

  float acc[2][4] = {};
  for (int k0 = 0; k0 < DD; k0 += 16) {
    const float2 xv = *(const float2*)&X[(m0 + xr) * DD + k0 + xc];
    const float4 wv = *(const float4*)&W[(e0 + wr) * DD + k0 + wc];
    __syncthreads();
    Xs[xc][xr] = xv.x; Xs[xc + 1][xr] = xv.y;
    Ws[wc][wr] = wv.x; Ws[wc + 1][wr] = wv.y; Ws[wc + 2][wr] = wv.z; Ws[wc + 3][wr] = wv.w;
    __syncthreads();
#pragma unroll
    for (int k = 0; k < 16; ++k) {
      const float2 a  = *(const float2*)&Xs[k][r0];
      const float4 bq = *(const float4*)&Ws[k][c0];
      acc[0][0] = fmaf(a.x, bq.x, acc[0][0]); acc[0][1] = fmaf(a.x, bq.y, acc[0][1]);
      acc[0][2] = fmaf(a.x, bq.z, acc[0][2]); acc[0][3] = fmaf(a.x, bq.w, acc[0][3]);
      acc[1][0] = fmaf(a.y, bq.x, acc[1][0]); acc[1][1] = fmaf(a.y, bq.y, acc[1][1]);
      acc[1][2] = fmaf(a.y, bq.z, acc[1][2]); acc[1][3] = fmaf(a.y, bq.w, acc[1][3]);
    }
  }
#pragma unroll
  for (int i = 0; i < 2; ++i) {
    float4 o;
    o.x = fast_exp2(acc[i][0] * TWO_LOG2E);
    o.y = fast_exp2(acc[i][1] * TWO_LOG2E);
    o.z = fast_exp2(acc[i][2] * TWO_LOG2E);
    o.w = fast_exp2(acc[i][3] * TWO_LOG2E);
    *(float4*)&E[(m0 + r0 + i) * DD + e0 + c0] = o;
  }
}

// One block per (b, 2 q-rows): 512 blocks x 512 threads (16 waves/CU).
// tanh(a+b) = 1 - 2/(Ea*Eb+1); thread owns one k for both q-rows.
__global__ __launch_bounds__(512) void attn_main(const float* __restrict__ Ea,
                                                 const float* __restrict__ Eb,
                                                 const float* __restrict__ vvec,
                                                 const float* __restrict__ value,
                                                 const int* __restrict__ mask,
                                                 float* __restrict__ ctx_out,
                                                 float* __restrict__ attn_out) {
  __shared__ float ebs[2][DD];
  __shared__ float vsh[DD];
  __shared__ float sc[2][LKK];
  __shared__ float red[2][4];
  __shared__ float red2[2][4];
  const int tid = threadIdx.x;
  const int b  = blockIdx.x >> 7;
  const int q0 = (blockIdx.x & 127) << 1;

  // stage Eb rows (2x256) and v (256)
  if (tid < 128) {
    const int q = tid >> 6, c4 = (tid & 63) << 2;
    *(float4*)&ebs[q][c4] = *(const float4*)&Eb[(b * LQQ + q0 + q) * DD + c4];
  } else if (tid < 192) {
    const int c4 = (tid - 128) << 2;
    *(float4*)&vsh[c4] = *(const float4*)&vvec[c4];
  }
  __syncthreads();

  // Sv = sum_d v[d]  (uniform broadcast reads, trivial)
  float Sv = 0.f;
#pragma unroll 8
  for (int d4 = 0; d4 < 64; ++d4) {
    const float4 vv = *(const float4*)&vsh[d4 << 2];
    Sv += (vv.x + vv.y) + (vv.z + vv.w);
  }

  // scores: thread owns k = tid for q0 and q0+1
  const int k = tid;
  const float* __restrict__ eap = &Ea[(b * LKK + k) * DD];
  float a0 = 0.f, a1 = 0.f;
  for (int d4 = 0; d4 < 64; ++d4) {
    const float4 ea = *(const float4*)&eap[d4 << 2];
    const float4 vv = *(const float4*)&vsh[d4 << 2];
    const float4 e0 = *(const float4*)&ebs[0][d4 << 2];
    const float4 e1 = *(const float4*)&ebs[1][d4 << 2];
    a0 += vv.x * fast_rcp(fmaf(ea.x, e0.x, 1.f))
        + vv.y * fast_rcp(fmaf(ea.y, e0.y, 1.f))
        + vv.z * fast_rcp(fmaf(ea.z, e0.z, 1.f))
        + vv.w * fast_rcp(fmaf(ea.w, e0.w, 1.f));
    a1 += vv.x * fast_rcp(fmaf(ea.x, e1.x, 1.f))
        + vv.y * fast_rcp(fmaf(ea.y, e1.y, 1.f))
        + vv.z * fast_rcp(fmaf(ea.z, e1.z, 1.f))
        + vv.w * fast_rcp(fmaf(ea.w, e1.w, 1.f));
  }
  const float inv_scale = 0.0625f;  // 1/sqrt(256)
  float s0 = (Sv - 2.f * a0) * inv_scale;
  float s1 = (Sv - 2.f * a1) * inv_scale;
  const int mrow = (b * LQQ + q0) * LKK;
  if (mask[mrow + k] == 0)       s0 = -1e10f;
  if (mask[mrow + LKK + k] == 0) s1 = -1e10f;
  sc[0][k] = s0;
  sc[1][k] = s1;
  __syncthreads();

  // softmax: thread handles (q = tid>>8, j = tid&255) -> sc[q][j], sc[q][j+256]
  const int q = tid >> 8, j = tid & 255;
  const int w4 = (tid >> 6) & 3;          // wave index within q-group
  float x0 = sc[q][j], x1 = sc[q][j + 256];
  float mx = fmaxf(x0, x1);
#pragma unroll
  for (int off = 32; off; off >>= 1) mx = fmaxf(mx, __shfl_xor(mx, off));
  if ((tid & 63) == 0) red[q][w4] = mx;
  __syncthreads();
  mx = fmaxf(fmaxf(red[q][0], red[q][1]), fmaxf(red[q][2], red[q][3]));
  float p0 = fast_exp2((x0 - mx) * LOG2E);
  float p1 = fast_exp2((x1 - mx) * LOG2E);
  float sum = p0 + p1;
#pragma unroll
  for (int off = 32; off; off >>= 1) sum += __shfl_xor(sum, off);
  if ((tid & 63) == 0) red2[q][w4] = sum;
  __syncthreads();
  sum = (red2[q][0] + red2[q][1]) + (red2[q][2] + red2[q][3]);
  const float inv_sum = fast_rcp(sum);
  p0 *= inv_sum; p1 *= inv_sum;
  const int arow = (b * LQQ + q0 + q) * LKK;
  attn_out[arow + j]       = p0;
  attn_out[arow + j + 256] = p1;
  sc[q][j]       = p0;
  sc[q][j + 256] = p1;
  __syncthreads();

  // context[q, d] = sum_k attn[q,k] * value[b,k,d]; thread: (q = tid>>8, d = tid&255)
  const int d = j;
  float c = 0.f;
  const float* __restrict__ vb = &value[b * LKK * DD + d];
#pragma unroll 8
  for (int kk = 0; kk < LKK; ++kk) c = fmaf(sc[q][kk], vb[kk * DD], c);
  ctx_out[(b * LQQ + q0 + q) * DD + d] = c;
}

extern "C" void kernel_launch(void* const* d_in, const int* in_sizes, int n_in,
                              void* d_out, int out_size, void* d_ws, size_t ws_size,
                              hipStream_t stream) {
  const float* query = (const float*)d_in[0];
  const float* key   = (const float*)d_in[1];
  const float* value = (const float*)d_in[2];
  const float* W1    = (const float*)d_in[3];
  const float* W2    = (const float*)d_in[4];
  const float* v     = (const float*)d_in[5];
  const int*   mask  = (const int*)d_in[6];

  float* out      = (float*)d_out;
  float* ctx_out  = out;                       // [B, LQ, D]
  float* attn_out = out + BB * LQQ * DD;       // [B, LQ, LK]

  float* Ea = (float*)d_ws;                    // [B*LK, D] = 2 MB
  float* Eb = Ea + BB * LKK * DD;              // [B*LQ, D] = 1 MB

  dim3 g1(BB * LKK / 32 + BB * LQQ / 32, DD / 64);   // (96, 4) = 384 blocks
  gemm_expk2<<<g1, 256, 0, stream>>>(key, query, W1, W2, Ea, Eb);

  attn_main<<<512, 512, 0, stream>>>(Ea, Eb, v, value, mask, ctx_out, attn_out);
}

// Round 3
// 62.931 us; speedup vs baseline: 1.4220x; 1.1998x over previous
//
#include <hip/hip_runtime.h>
#include <math.h>

#define DD  256
#define LKK 512
#define LQQ 256
#define BB  4

constexpr float TWO_LOG2E = 2.8853900817779268f;  // 2*log2(e)
constexpr float LOG2E     = 1.4426950408889634f;

__device__ __forceinline__ float fast_rcp(float x)  { return __builtin_amdgcn_rcpf(x); }
__device__ __forceinline__ float fast_exp2(float x) { return __builtin_amdgcn_exp2f(x); }

#define COMP(v,u) ((u)==0?(v).x:(u)==1?(v).y:(u)==2?(v).z:(v).w)

// EaT[b][e][k] = exp(2 * key[b,k,:] . W1[e,:])  (d-major / transposed)
// Eb [b*LQ+q][e] = exp(2 * query[b,q,:] . W2[e,:])  (row-major)
__global__ __launch_bounds__(256) void gemm_expk2(const float* __restrict__ key,
                                                  const float* __restrict__ query,
                                                  const float* __restrict__ W1,
                                                  const float* __restrict__ W2,
                                                  float* __restrict__ EaT,
                                                  float* __restrict__ Eb) {
  __shared__ float Xs[16][36];
  __shared__ float Ws[16][68];
  const int tid = threadIdx.x;
  const bool isK = blockIdx.x < (BB * LKK / 32);
  const float* __restrict__ X = isK ? key : query;
  const float* __restrict__ W = isK ? W1 : W2;
  const int m0 = (isK ? blockIdx.x : blockIdx.x - BB * LKK / 32) * 32;
  const int e0 = blockIdx.y * 64;

  const int r0 = (tid >> 4) << 1;   // 0..30
  const int c0 = (tid & 15) << 2;   // 0..60
  const int xr = tid >> 3, xc = (tid & 7) << 1;
  const int wr = tid >> 2, wc = (tid & 3) << 2;

  float acc[2][4] = {};
  for (int k0 = 0; k0 < DD; k0 += 16) {
    const float2 xv = *(const float2*)&X[(m0 + xr) * DD + k0 + xc];
    const float4 wv = *(const float4*)&W[(e0 + wr) * DD + k0 + wc];
    __syncthreads();
    Xs[xc][xr] = xv.x; Xs[xc + 1][xr] = xv.y;
    Ws[wc][wr] = wv.x; Ws[wc + 1][wr] = wv.y; Ws[wc + 2][wr] = wv.z; Ws[wc + 3][wr] = wv.w;
    __syncthreads();
#pragma unroll
    for (int k = 0; k < 16; ++k) {
      const float2 a  = *(const float2*)&Xs[k][r0];
      const float4 bq = *(const float4*)&Ws[k][c0];
      acc[0][0] = fmaf(a.x, bq.x, acc[0][0]); acc[0][1] = fmaf(a.x, bq.y, acc[0][1]);
      acc[0][2] = fmaf(a.x, bq.z, acc[0][2]); acc[0][3] = fmaf(a.x, bq.w, acc[0][3]);
      acc[1][0] = fmaf(a.y, bq.x, acc[1][0]); acc[1][1] = fmaf(a.y, bq.y, acc[1][1]);
      acc[1][2] = fmaf(a.y, bq.z, acc[1][2]); acc[1][3] = fmaf(a.y, bq.w, acc[1][3]);
    }
  }
  if (isK) {
    const int b = m0 >> 9;
    const int kloc = (m0 & 511) + r0;
#pragma unroll
    for (int j = 0; j < 4; ++j) {
      float2 o;
      o.x = fast_exp2(acc[0][j] * TWO_LOG2E);
      o.y = fast_exp2(acc[1][j] * TWO_LOG2E);
      *(float2*)&EaT[b * (DD * LKK) + (e0 + c0 + j) * LKK + kloc] = o;
    }
  } else {
#pragma unroll
    for (int i = 0; i < 2; ++i) {
      float4 o;
      o.x = fast_exp2(acc[i][0] * TWO_LOG2E);
      o.y = fast_exp2(acc[i][1] * TWO_LOG2E);
      o.z = fast_exp2(acc[i][2] * TWO_LOG2E);
      o.w = fast_exp2(acc[i][3] * TWO_LOG2E);
      *(float4*)&Eb[(m0 + r0 + i) * DD + e0 + c0] = o;
    }
  }
}

// One block per (b, 4 q-rows): 256 blocks x 512 threads.
// Scores: thread = (d-quarter, 4 k, all 4 q). Then softmax + context in-block.
__global__ __launch_bounds__(512) void attn_fused(const float* __restrict__ EaT,
                                                  const float* __restrict__ Eb,
                                                  const float* __restrict__ vvec,
                                                  const float* __restrict__ value,
                                                  const int* __restrict__ mask,
                                                  float* __restrict__ ctx_out,
                                                  float* __restrict__ attn_out) {
  __shared__ float ebs[4][DD];        // 4 KB
  __shared__ float vsh[DD];           // 1 KB
  __shared__ float sc[4][LKK];        // 8 KB
  __shared__ float scratch[16 * 516]; // 33 KB (dq-reduce, later ctx-reduce)
  __shared__ float redm[4][2], reds[4][2];

  const int tid = threadIdx.x;
  const int b  = blockIdx.x >> 6;
  const int q0 = (blockIdx.x & 63) << 2;

  // stage Eb rows (4x256) and v
  if (tid < 256) {
    const int qi = tid >> 6, d4 = (tid & 63) << 2;
    *(float4*)&ebs[qi][d4] = *(const float4*)&Eb[(b * LQQ + q0 + qi) * DD + d4];
  } else if (tid < 320) {
    const int d4 = (tid - 256) << 2;
    *(float4*)&vsh[d4] = *(const float4*)&vvec[d4];
  }
  __syncthreads();

  // Sv = sum_d v[d] (uniform broadcast reads)
  float Sv = 0.f;
#pragma unroll
  for (int d4 = 0; d4 < DD; d4 += 4) {
    const float4 vv = *(const float4*)&vsh[d4];
    Sv += (vv.x + vv.y) + (vv.z + vv.w);
  }

  // ---- scores: acc[qi][ki] over this thread's 64-d quarter ----
  const int dq = tid >> 7;          // 0..3
  const int k4 = (tid & 127) << 2;  // 0..508
  const int db = dq << 6;           // d base
  float acc[4][4] = {};
  const float* __restrict__ ea = &EaT[b * (DD * LKK) + db * LKK + k4];
#pragma unroll 2
  for (int i = 0; i < 64; i += 4) {
    const float4 vv  = *(const float4*)&vsh[db + i];
    const float4 e0q = *(const float4*)&ebs[0][db + i];
    const float4 e1q = *(const float4*)&ebs[1][db + i];
    const float4 e2q = *(const float4*)&ebs[2][db + i];
    const float4 e3q = *(const float4*)&ebs[3][db + i];
#pragma unroll
    for (int u = 0; u < 4; ++u) {
      const float4 a = *(const float4*)ea; ea += LKK;
      const float vd = COMP(vv, u);
      const float b0 = COMP(e0q, u), b1 = COMP(e1q, u), b2 = COMP(e2q, u), b3 = COMP(e3q, u);
      acc[0][0] = fmaf(vd, fast_rcp(fmaf(a.x, b0, 1.f)), acc[0][0]);
      acc[0][1] = fmaf(vd, fast_rcp(fmaf(a.y, b0, 1.f)), acc[0][1]);
      acc[0][2] = fmaf(vd, fast_rcp(fmaf(a.z, b0, 1.f)), acc[0][2]);
      acc[0][3] = fmaf(vd, fast_rcp(fmaf(a.w, b0, 1.f)), acc[0][3]);
      acc[1][0] = fmaf(vd, fast_rcp(fmaf(a.x, b1, 1.f)), acc[1][0]);
      acc[1][1] = fmaf(vd, fast_rcp(fmaf(a.y, b1, 1.f)), acc[1][1]);
      acc[1][2] = fmaf(vd, fast_rcp(fmaf(a.z, b1, 1.f)), acc[1][2]);
      acc[1][3] = fmaf(vd, fast_rcp(fmaf(a.w, b1, 1.f)), acc[1][3]);
      acc[2][0] = fmaf(vd, fast_rcp(fmaf(a.x, b2, 1.f)), acc[2][0]);
      acc[2][1] = fmaf(vd, fast_rcp(fmaf(a.y, b2, 1.f)), acc[2][1]);
      acc[2][2] = fmaf(vd, fast_rcp(fmaf(a.z, b2, 1.f)), acc[2][2]);
      acc[2][3] = fmaf(vd, fast_rcp(fmaf(a.w, b2, 1.f)), acc[2][3]);
      acc[3][0] = fmaf(vd, fast_rcp(fmaf(a.x, b3, 1.f)), acc[3][0]);
      acc[3][1] = fmaf(vd, fast_rcp(fmaf(a.y, b3, 1.f)), acc[3][1]);
      acc[3][2] = fmaf(vd, fast_rcp(fmaf(a.z, b3, 1.f)), acc[3][2]);
      acc[3][3] = fmaf(vd, fast_rcp(fmaf(a.w, b3, 1.f)), acc[3][3]);
    }
  }
  // write dq-partials (conflict-free b128)
#pragma unroll
  for (int qi = 0; qi < 4; ++qi) {
    *(float4*)&scratch[(dq * 4 + qi) * 516 + k4] =
        make_float4(acc[qi][0], acc[qi][1], acc[qi][2], acc[qi][3]);
  }
  __syncthreads();

  // ---- combine partials -> masked scaled scores in sc ----
  {
    const int qi = tid >> 7, j = (tid & 127) << 2;
    float4 s = make_float4(0.f, 0.f, 0.f, 0.f);
#pragma unroll
    for (int d = 0; d < 4; ++d) {
      const float4 r = *(const float4*)&scratch[(d * 4 + qi) * 516 + j];
      s.x += r.x; s.y += r.y; s.z += r.z; s.w += r.w;
    }
    const float inv_scale = 0.0625f;  // 1/sqrt(256)
    s.x = (Sv - 2.f * s.x) * inv_scale;
    s.y = (Sv - 2.f * s.y) * inv_scale;
    s.z = (Sv - 2.f * s.z) * inv_scale;
    s.w = (Sv - 2.f * s.w) * inv_scale;
    const int4 m4 = *(const int4*)&mask[(b * LQQ + q0 + qi) * LKK + j];
    if (m4.x == 0) s.x = -1e10f;
    if (m4.y == 0) s.y = -1e10f;
    if (m4.z == 0) s.z = -1e10f;
    if (m4.w == 0) s.w = -1e10f;
    *(float4*)&sc[qi][j] = s;
  }
  __syncthreads();

  // ---- softmax: 2 waves per q-row ----
  {
    const int qi = tid >> 7, j = (tid & 127) << 2;
    const int w2 = (tid >> 6) & 1;
    float4 x = *(const float4*)&sc[qi][j];
    float mx = fmaxf(fmaxf(x.x, x.y), fmaxf(x.z, x.w));
#pragma unroll
    for (int off = 32; off; off >>= 1) mx = fmaxf(mx, __shfl_xor(mx, off));
    if ((tid & 63) == 0) redm[qi][w2] = mx;
    __syncthreads();
    mx = fmaxf(redm[qi][0], redm[qi][1]);
    float4 p;
    p.x = fast_exp2((x.x - mx) * LOG2E);
    p.y = fast_exp2((x.y - mx) * LOG2E);
    p.z = fast_exp2((x.z - mx) * LOG2E);
    p.w = fast_exp2((x.w - mx) * LOG2E);
    float sum = (p.x + p.y) + (p.z + p.w);
#pragma unroll
    for (int off = 32; off; off >>= 1) sum += __shfl_xor(sum, off);
    if ((tid & 63) == 0) reds[qi][w2] = sum;
    __syncthreads();
    sum = reds[qi][0] + reds[qi][1];
    const float inv = fast_rcp(sum);
    p.x *= inv; p.y *= inv; p.z *= inv; p.w *= inv;
    *(float4*)&attn_out[(b * LQQ + q0 + qi) * LKK + j] = p;
    *(float4*)&sc[qi][j] = p;
  }
  __syncthreads();

  // ---- context: thread = (k-eighth, float4 d, all 4 q) ----
  {
    const int kh = tid >> 6, d4i = (tid & 63) << 2;
    const int kbase = kh << 6;
    float4 c[4] = {};
    const float* __restrict__ vb = &value[(b * LKK + kbase) * DD + d4i];
    for (int kk = 0; kk < 64; kk += 4) {
      const float4 p0 = *(const float4*)&sc[0][kbase + kk];
      const float4 p1 = *(const float4*)&sc[1][kbase + kk];
      const float4 p2 = *(const float4*)&sc[2][kbase + kk];
      const float4 p3 = *(const float4*)&sc[3][kbase + kk];
#pragma unroll
      for (int u = 0; u < 4; ++u) {
        const float4 vv = *(const float4*)vb; vb += DD;
        const float a0 = COMP(p0, u), a1 = COMP(p1, u), a2 = COMP(p2, u), a3 = COMP(p3, u);
        c[0].x = fmaf(a0, vv.x, c[0].x); c[0].y = fmaf(a0, vv.y, c[0].y);
        c[0].z = fmaf(a0, vv.z, c[0].z); c[0].w = fmaf(a0, vv.w, c[0].w);
        c[1].x = fmaf(a1, vv.x, c[1].x); c[1].y = fmaf(a1, vv.y, c[1].y);
        c[1].z = fmaf(a1, vv.z, c[1].z); c[1].w = fmaf(a1, vv.w, c[1].w);
        c[2].x = fmaf(a2, vv.x, c[2].x); c[2].y = fmaf(a2, vv.y, c[2].y);
        c[2].z = fmaf(a2, vv.z, c[2].z); c[2].w = fmaf(a2, vv.w, c[2].w);
        c[3].x = fmaf(a3, vv.x, c[3].x); c[3].y = fmaf(a3, vv.y, c[3].y);
        c[3].z = fmaf(a3, vv.z, c[3].z); c[3].w = fmaf(a3, vv.w, c[3].w);
      }
    }
#pragma unroll
    for (int qi = 0; qi < 4; ++qi)
      *(float4*)&scratch[(kh * 4 + qi) * DD + d4i] = c[qi];
  }
  __syncthreads();

  if (tid < 256) {
    const int qi = tid >> 6, d4 = (tid & 63) << 2;
    float4 s = make_float4(0.f, 0.f, 0.f, 0.f);
#pragma unroll
    for (int kh2 = 0; kh2 < 8; ++kh2) {
      const float4 r = *(const float4*)&scratch[(kh2 * 4 + qi) * DD + d4];
      s.x += r.x; s.y += r.y; s.z += r.z; s.w += r.w;
    }
    *(float4*)&ctx_out[(b * LQQ + q0 + qi) * DD + d4] = s;
  }
}

extern "C" void kernel_launch(void* const* d_in, const int* in_sizes, int n_in,
                              void* d_out, int out_size, void* d_ws, size_t ws_size,
                              hipStream_t stream) {
  const float* query = (const float*)d_in[0];
  const float* key   = (const float*)d_in[1];
  const float* value = (const float*)d_in[2];
  const float* W1    = (const float*)d_in[3];
  const float* W2    = (const float*)d_in[4];
  const float* v     = (const float*)d_in[5];
  const int*   mask  = (const int*)d_in[6];

  float* out      = (float*)d_out;
  float* ctx_out  = out;                       // [B, LQ, D]
  float* attn_out = out + BB * LQQ * DD;       // [B, LQ, LK]

  float* EaT = (float*)d_ws;                   // [B][D][LK] = 2 MB
  float* Eb  = EaT + BB * DD * LKK;            // [B*LQ][D]  = 1 MB

  dim3 g1(BB * LKK / 32 + BB * LQQ / 32, DD / 64);   // (96, 4)
  gemm_expk2<<<g1, 256, 0, stream>>>(key, query, W1, W2, EaT, Eb);

  attn_fused<<<BB * LQQ / 4, 512, 0, stream>>>(EaT, Eb, v, value, mask, ctx_out, attn_out);
}